// Round 1
// baseline (5322.736 us; speedup 1.0000x reference)
//
#include <hip/hip_runtime.h>
#include <hip/hip_bf16.h>
#include <cstdint>

typedef unsigned short u16;
typedef unsigned int u32;
typedef float f32x4 __attribute__((ext_vector_type(4)));
typedef __bf16 bf16x8 __attribute__((ext_vector_type(8)));
typedef u16 u16x4 __attribute__((ext_vector_type(4)));

#define DEVI __device__ __forceinline__

constexpr int DMODEL = 768;
constexpr int NH = 12;
constexpr int NL = 12;
constexpr int FF = 3072;
constexpr int VOCAB = 50257;
constexpr int VPAD = 50304;   // pad vocab to multiple of 128 for GEMM tiles
constexpr int BB = 2;
constexpr int TT = 1024;
constexpr int MROWS = BB * TT;   // 2048

// ---------- bf16 helpers (RNE) ----------
DEVI u16 f2bf(float f) {
    u32 u = __builtin_bit_cast(u32, f);
    u32 r = (u + 0x7fffu + ((u >> 16) & 1u)) >> 16;
    return (u16)r;
}
DEVI float bf2f(u16 h) { return __builtin_bit_cast(float, (u32)h << 16); }
DEVI void split2(float v, u16& hi, u16& lo) { hi = f2bf(v); lo = f2bf(v - bf2f(hi)); }

// async global->LDS, 16B per lane. LDS dest must be wave-uniform base + lane*16.
DEVI void gload16(const void* g, void* l) {
    __builtin_amdgcn_global_load_lds(
        (__attribute__((address_space(1))) u32*)(uintptr_t)g,
        (__attribute__((address_space(3))) u32*)l, 16, 0, 0);
}

// ---------- tok_emb -> padded bf16 (hi only, plain bf16 LM head) ----------
__global__ __launch_bounds__(256) void temb_kernel(const float* __restrict__ emb,
                                                   u16* __restrict__ out) {
    int gid = blockIdx.x * 256 + threadIdx.x;     // over VPAD*768/4
    int i4 = gid * 4;
    int row = i4 / DMODEL;
    u16x4 o;
    if (row < VOCAB) {
        f32x4 v = *(const f32x4*)&emb[i4];
        o[0] = f2bf(v[0]); o[1] = f2bf(v[1]); o[2] = f2bf(v[2]); o[3] = f2bf(v[3]);
    } else {
        o[0] = 0; o[1] = 0; o[2] = 0; o[3] = 0;
    }
    *(u16x4*)&out[i4] = o;
}

// ---------- embedding gather + sinusoidal PE (fp32) ----------
__global__ __launch_bounds__(256) void embed_kernel(const int* __restrict__ idx,
                                                    const float* __restrict__ emb,
                                                    float* __restrict__ x) {
    int gid = blockIdx.x * 256 + threadIdx.x;     // over 2048*768
    int d = gid % DMODEL;
    int bt = gid / DMODEL;
    int tpos = bt % TT;
    int tok = idx[bt];
    float freq = expf(-(float)(d & ~1) * (9.210340371976184f / (float)DMODEL));
    float ang = (float)tpos * freq;
    float pe = (d & 1) ? cosf(ang) : sinf(ang);
    x[gid] = emb[(int64_t)tok * DMODEL + d] + pe;
}

// ---------- weight transpose + hi/lo split: in fp32 [Kd][Nd] -> out bf16 [Nd][Kd] ----------
__global__ __launch_bounds__(256) void tconv_kernel(const float* __restrict__ W,
                                                    u16* __restrict__ hi, u16* __restrict__ lo,
                                                    int Kd, int Nd) {
    __shared__ float tile[32][33];
    int tx = threadIdx.x & 31, ty = threadIdx.x >> 5;   // 32 x 8
    int nb = blockIdx.x * 32, kb = blockIdx.y * 32;
#pragma unroll
    for (int j = 0; j < 4; j++)
        tile[ty + j * 8][tx] = W[(int64_t)(kb + ty + j * 8) * Nd + nb + tx];
    __syncthreads();
#pragma unroll
    for (int j = 0; j < 4; j++) {
        float v = tile[tx][ty + j * 8];
        u16 h, l2; split2(v, h, l2);
        int64_t o = (int64_t)(nb + ty + j * 8) * Kd + kb + tx;
        hi[o] = h; lo[o] = l2;
    }
}

// ---------- LayerNorm (fp32 in) -> bf16 hi/lo ----------
__global__ __launch_bounds__(256) void ln_kernel(const float* __restrict__ x,
                                                 const float* __restrict__ w,
                                                 const float* __restrict__ b,
                                                 u16* __restrict__ hhi, u16* __restrict__ hlo) {
    int row = blockIdx.x;
    int t = threadIdx.x;
    const float* xr = x + (int64_t)row * DMODEL;
    float v0 = xr[t], v1 = xr[t + 256], v2 = xr[t + 512];
    float s = v0 + v1 + v2;
#pragma unroll
    for (int o = 32; o > 0; o >>= 1) s += __shfl_xor(s, o);
    __shared__ float red[4], red2[4];
    if ((t & 63) == 0) red[t >> 6] = s;
    __syncthreads();
    s = red[0] + red[1] + red[2] + red[3];
    float mu = s * (1.0f / (float)DMODEL);
    float d0 = v0 - mu, d1 = v1 - mu, d2 = v2 - mu;
    float q = d0 * d0 + d1 * d1 + d2 * d2;
#pragma unroll
    for (int o = 32; o > 0; o >>= 1) q += __shfl_xor(q, o);
    if ((t & 63) == 0) red2[t >> 6] = q;
    __syncthreads();
    q = red2[0] + red2[1] + red2[2] + red2[3];
    float rs = rsqrtf(q * (1.0f / (float)DMODEL) + 1e-5f);
    u16 h, l2;
    int64_t base = (int64_t)row * DMODEL;
    split2(d0 * rs * w[t] + b[t], h, l2);             hhi[base + t] = h;       hlo[base + t] = l2;
    split2(d1 * rs * w[t + 256] + b[t + 256], h, l2); hhi[base + t + 256] = h; hlo[base + t + 256] = l2;
    split2(d2 * rs * w[t + 512] + b[t + 512], h, l2); hhi[base + t + 512] = h; hlo[base + t + 512] = l2;
}

// ---------- causal softmax row kernel: S fp32 [24][1024][1024] -> P bf16 ----------
__global__ __launch_bounds__(256) void softmax_kernel(const float* __restrict__ S,
                                                      u16* __restrict__ P) {
    const int r = blockIdx.x, z = blockIdx.y, t = threadIdx.x;
    const int64_t base = ((int64_t)z * TT + r) * TT;
    f32x4 v = *(const f32x4*)(S + base + t * 4);
    float vv[4];
    float m = -3.4e38f;
#pragma unroll
    for (int i = 0; i < 4; i++) {
        int j = t * 4 + i;
        vv[i] = (j <= r) ? v[i] : -3.4e38f;
        m = fmaxf(m, vv[i]);
    }
#pragma unroll
    for (int o = 32; o > 0; o >>= 1) m = fmaxf(m, __shfl_xor(m, o));
    __shared__ float redm[4], reds[4];
    if ((t & 63) == 0) redm[t >> 6] = m;
    __syncthreads();
    m = fmaxf(fmaxf(redm[0], redm[1]), fmaxf(redm[2], redm[3]));
    float e[4];
    float s = 0.f;
#pragma unroll
    for (int i = 0; i < 4; i++) {
        int j = t * 4 + i;
        e[i] = (j <= r) ? expf(vv[i] - m) : 0.f;
        s += e[i];
    }
#pragma unroll
    for (int o = 32; o > 0; o >>= 1) s += __shfl_xor(s, o);
    if ((t & 63) == 0) reds[t >> 6] = s;
    __syncthreads();
    s = reds[0] + reds[1] + reds[2] + reds[3];
    float inv = 1.f / s;
    u16x4 pw;
#pragma unroll
    for (int i = 0; i < 4; i++) pw[i] = f2bf(e[i] * inv);
    *(u16x4*)(P + base + t * 4) = pw;
}

// ---------- V transpose: qkv bf16 [2048][2304] -> Vt bf16 [24][64][1024] ----------
__global__ __launch_bounds__(256) void vt_kernel(const u16* __restrict__ qkvhi,
                                                 u16* __restrict__ Vt) {
    int gid = blockIdx.x * 256 + threadIdx.x;   // 24*64*1024
    int tpos = gid & 1023;
    int rest = gid >> 10;
    int d = rest & 63;
    int zz = rest >> 6;
    int b = zz / NH, h = zz % NH;
    Vt[gid] = qkvhi[((int64_t)(b * TT + tpos)) * (3 * DMODEL) + 2 * DMODEL + h * 64 + d];
}

// ---------- the GEMM: C[M,N] = A[M,K] * B^T[N,K] (both bf16, optional hi/lo split) ----------
// EPI: 0 = fp32 store (x alpha), 1 = fp32 store + residual, 2 = fp32 + bias + residual,
//      3 = bf16 hi/lo split store, 4 = bias + exact GELU + bf16 hi/lo split store
// CMODE: 0 none, 1 = causal block skip (scores), 2 = causal K limit (PV)
template <int BN_, bool SPLIT, int EPI, int CMODE>
__global__ __launch_bounds__(256)
void gemm_bt(const u16* __restrict__ Ahi, const u16* __restrict__ Alo, int lda, long long sAb, long long sAh,
             const u16* __restrict__ Bhi, const u16* __restrict__ Blo, int ldb, long long sBb, long long sBh,
             float* Cf, u16* Chi, u16* Clo, int ldc, long long sCb, long long sCh,
             const float* __restrict__ bias, const float* resid,
             int K, int Nreal, float alpha, int H) {
    static_assert(BN_ == 128 || BN_ == 64, "");
    constexpr int BM = 128, BK = 32;
    constexpr int WCOLS = (BN_ == 128) ? 2 : 1;
    constexpr int WM = (BN_ == 128) ? 64 : 32;
    constexpr int WN = 64;
    constexpr int MF = WM / 16, NF = WN / 16;

    const int bm = blockIdx.x, bn = blockIdx.y, z = blockIdx.z;
    if constexpr (CMODE == 1) {
        if (bn * BN_ >= (bm + 1) * BM) return;   // fully masked tile
    }
    const int t = (int)threadIdx.x;
    const int w = t >> 6, l = t & 63, lr = l & 15, lg = l >> 4;
    const int wr = w / WCOLS, wc = w % WCOLS;

    const int bi = z / H, hh = z % H;
    const long long baseA = (long long)bi * sAb + (long long)hh * sAh;
    const long long baseB = (long long)bi * sBb + (long long)hh * sBh;
    const long long baseC = (long long)bi * sCb + (long long)hh * sCh;

    __shared__ __align__(16) u16 sAhi[BM * BK];
    __shared__ __align__(16) u16 sBhi[BN_ * BK];
    __shared__ __align__(16) u16 sAlo[SPLIT ? BM * BK : 8];
    __shared__ __align__(16) u16 sBlo[SPLIT ? BN_ * BK : 8];

    const int srow = t >> 2, scol = (t & 3) * 8;   // staging: 4 lanes x 8 bf16 per row
    const u16* gA = Ahi + baseA + (long long)(bm * BM + srow) * lda + scol;
    const u16* gB = Bhi + baseB + (long long)(bn * BN_ + srow) * ldb + scol;
    const u16* gAl = nullptr;
    const u16* gBl = nullptr;
    if constexpr (SPLIT) {
        gAl = Alo + baseA + (long long)(bm * BM + srow) * lda + scol;
        gBl = Blo + baseB + (long long)(bn * BN_ + srow) * ldb + scol;
    }

    int kEnd = K;
    if constexpr (CMODE == 2) {
        int lim = (bm + 1) * BM;
        kEnd = (K < lim) ? K : lim;
    }
    const int nk = kEnd / BK;

    f32x4 acc[MF][NF];
#pragma unroll
    for (int a = 0; a < MF; a++)
#pragma unroll
        for (int b2 = 0; b2 < NF; b2++)
#pragma unroll
            for (int i = 0; i < 4; i++) acc[a][b2][i] = 0.0f;

    const int aoff = (wr * WM + lr) * BK + lg * 8;
    const int boff = (wc * WN + lr) * BK + lg * 8;

    for (int kt = 0; kt < nk; ++kt) {
        const int k0 = kt * BK;
#pragma unroll
        for (int i = 0; i < BM / 64; i++)
            gload16(gA + (long long)i * 64 * lda + k0, &sAhi[(i * 64 + srow) * BK + scol]);
#pragma unroll
        for (int i = 0; i < BN_ / 64; i++)
            gload16(gB + (long long)i * 64 * ldb + k0, &sBhi[(i * 64 + srow) * BK + scol]);
        if constexpr (SPLIT) {
#pragma unroll
            for (int i = 0; i < BM / 64; i++)
                gload16(gAl + (long long)i * 64 * lda + k0, &sAlo[(i * 64 + srow) * BK + scol]);
#pragma unroll
            for (int i = 0; i < BN_ / 64; i++)
                gload16(gBl + (long long)i * 64 * ldb + k0, &sBlo[(i * 64 + srow) * BK + scol]);
        }
        __syncthreads();   // drains vmcnt: LDS tiles ready

        bf16x8 ah[MF], bh[NF];
#pragma unroll
        for (int m = 0; m < MF; m++) ah[m] = *(const bf16x8*)&sAhi[aoff + m * 16 * BK];
#pragma unroll
        for (int n = 0; n < NF; n++) bh[n] = *(const bf16x8*)&sBhi[boff + n * 16 * BK];

        if constexpr (SPLIT) {
            bf16x8 al[MF], bl[NF];
#pragma unroll
            for (int m = 0; m < MF; m++) al[m] = *(const bf16x8*)&sAlo[aoff + m * 16 * BK];
#pragma unroll
            for (int n = 0; n < NF; n++) bl[n] = *(const bf16x8*)&sBlo[boff + n * 16 * BK];
#pragma unroll
            for (int m = 0; m < MF; m++)
#pragma unroll
                for (int n = 0; n < NF; n++) {
                    acc[m][n] = __builtin_amdgcn_mfma_f32_16x16x32_bf16(ah[m], bh[n], acc[m][n], 0, 0, 0);
                    acc[m][n] = __builtin_amdgcn_mfma_f32_16x16x32_bf16(ah[m], bl[n], acc[m][n], 0, 0, 0);
                    acc[m][n] = __builtin_amdgcn_mfma_f32_16x16x32_bf16(al[m], bh[n], acc[m][n], 0, 0, 0);
                }
        } else {
#pragma unroll
            for (int m = 0; m < MF; m++)
#pragma unroll
                for (int n = 0; n < NF; n++)
                    acc[m][n] = __builtin_amdgcn_mfma_f32_16x16x32_bf16(ah[m], bh[n], acc[m][n], 0, 0, 0);
        }
        __syncthreads();   // protect LDS reuse
    }

    // epilogue: C row = (lane>>4)*4 + i, col = lane&15  (m89/m91-verified)
    const int mBase = bm * BM + wr * WM + lg * 4;
    const int nBase = bn * BN_ + wc * WN + lr;
#pragma unroll
    for (int m = 0; m < MF; m++)
#pragma unroll
        for (int n = 0; n < NF; n++)
#pragma unroll
            for (int i = 0; i < 4; i++) {
                int mi = mBase + m * 16 + i;
                int ni = nBase + n * 16;
                if (ni < Nreal) {
                    float v = acc[m][n][i] * alpha;
                    long long off = baseC + (long long)mi * ldc + ni;
                    if constexpr (EPI == 0) {
                        Cf[off] = v;
                    } else if constexpr (EPI == 1) {
                        Cf[off] = v + resid[off];
                    } else if constexpr (EPI == 2) {
                        Cf[off] = v + bias[ni] + resid[off];
                    } else if constexpr (EPI == 3) {
                        u16 h2, l2; split2(v, h2, l2);
                        Chi[off] = h2; Clo[off] = l2;
                    } else if constexpr (EPI == 4) {
                        float tt = v + bias[ni];
                        float g = 0.5f * tt * (1.0f + erff(tt * 0.7071067811865476f));
                        u16 h2, l2; split2(g, h2, l2);
                        Chi[off] = h2; Clo[off] = l2;
                    }
                }
            }
}

// ---------------------------------------------------------------------------
extern "C" void kernel_launch(void* const* d_in, const int* in_sizes, int n_in,
                              void* d_out, int out_size, void* d_ws, size_t ws_size,
                              hipStream_t stream) {
    const int* idx        = (const int*)d_in[0];
    const float* tok_emb  = (const float*)d_in[1];
    const float* ln1_w    = (const float*)d_in[2];
    const float* ln1_b    = (const float*)d_in[3];
    const float* qkv_w    = (const float*)d_in[4];
    const float* out_w    = (const float*)d_in[5];
    const float* ln2_w    = (const float*)d_in[6];
    const float* ln2_b    = (const float*)d_in[7];
    const float* ff_w1    = (const float*)d_in[8];
    const float* ff_b1    = (const float*)d_in[9];
    const float* ff_w2    = (const float*)d_in[10];
    const float* ff_b2    = (const float*)d_in[11];
    const float* lnf_w    = (const float*)d_in[12];
    const float* lnf_b    = (const float*)d_in[13];
    float* logits = (float*)d_out;

    // workspace carve-up
    char* ws = (char*)d_ws;
    auto alloc = [&](size_t bytes) -> char* {
        char* p = ws;
        ws += (bytes + 255) & ~(size_t)255;
        return p;
    };
    u16* temb   = (u16*)alloc((size_t)VPAD * DMODEL * 2);
    float* xf   = (float*)alloc((size_t)MROWS * DMODEL * 4);
    u16* h_hi   = (u16*)alloc((size_t)MROWS * DMODEL * 2);
    u16* h_lo   = (u16*)alloc((size_t)MROWS * DMODEL * 2);
    u16* qkv_hi = (u16*)alloc((size_t)MROWS * 3 * DMODEL * 2);
    u16* qkv_lo = (u16*)alloc((size_t)MROWS * 3 * DMODEL * 2);
    u16* Vt     = (u16*)alloc((size_t)BB * NH * 64 * TT * 2);
    float* S    = (float*)alloc((size_t)BB * NH * TT * TT * 4);
    u16* P      = (u16*)alloc((size_t)BB * NH * TT * TT * 2);
    u16* O_hi   = (u16*)alloc((size_t)MROWS * DMODEL * 2);
    u16* O_lo   = (u16*)alloc((size_t)MROWS * DMODEL * 2);
    u16* g_hi   = (u16*)alloc((size_t)MROWS * FF * 2);
    u16* g_lo   = (u16*)alloc((size_t)MROWS * FF * 2);
    u16* wQhi   = (u16*)alloc((size_t)3 * DMODEL * DMODEL * 2);
    u16* wQlo   = (u16*)alloc((size_t)3 * DMODEL * DMODEL * 2);
    u16* wOhi   = (u16*)alloc((size_t)DMODEL * DMODEL * 2);
    u16* wOlo   = (u16*)alloc((size_t)DMODEL * DMODEL * 2);
    u16* wF1hi  = (u16*)alloc((size_t)DMODEL * FF * 2);
    u16* wF1lo  = (u16*)alloc((size_t)DMODEL * FF * 2);
    u16* wF2hi  = (u16*)alloc((size_t)DMODEL * FF * 2);
    u16* wF2lo  = (u16*)alloc((size_t)DMODEL * FF * 2);

    const long long ZA = (long long)TT * 3 * DMODEL;      // per-batch stride in qkv rows
    const long long ZS = (long long)NH * TT * TT;         // per-batch stride in S/P
    const long long ZV = (long long)NH * 64 * TT;         // per-batch stride in Vt

    // tok_emb -> padded bf16
    temb_kernel<<<(VPAD * DMODEL / 4) / 256, 256, 0, stream>>>(tok_emb, temb);
    // embedding + positional encoding
    embed_kernel<<<(MROWS * DMODEL) / 256, 256, 0, stream>>>(idx, tok_emb, xf);

    for (int l2 = 0; l2 < NL; l2++) {
        const float* qw = qkv_w + (int64_t)l2 * DMODEL * 3 * DMODEL;
        const float* ow = out_w + (int64_t)l2 * DMODEL * DMODEL;
        const float* w1 = ff_w1 + (int64_t)l2 * DMODEL * FF;
        const float* w2 = ff_w2 + (int64_t)l2 * FF * DMODEL;

        tconv_kernel<<<dim3(3 * DMODEL / 32, DMODEL / 32), 256, 0, stream>>>(qw, wQhi, wQlo, DMODEL, 3 * DMODEL);
        tconv_kernel<<<dim3(DMODEL / 32, DMODEL / 32), 256, 0, stream>>>(ow, wOhi, wOlo, DMODEL, DMODEL);
        tconv_kernel<<<dim3(FF / 32, DMODEL / 32), 256, 0, stream>>>(w1, wF1hi, wF1lo, DMODEL, FF);
        tconv_kernel<<<dim3(DMODEL / 32, FF / 32), 256, 0, stream>>>(w2, wF2hi, wF2lo, FF, DMODEL);

        // LN1
        ln_kernel<<<MROWS, 256, 0, stream>>>(xf, ln1_w + l2 * DMODEL, ln1_b + l2 * DMODEL, h_hi, h_lo);

        // qkv = h @ qkv_w   -> bf16 hi/lo
        gemm_bt<128, true, 3, 0><<<dim3(16, 18, 1), 256, 0, stream>>>(
            h_hi, h_lo, DMODEL, 0, 0,
            wQhi, wQlo, DMODEL, 0, 0,
            nullptr, qkv_hi, qkv_lo, 3 * DMODEL, 0, 0,
            nullptr, nullptr, DMODEL, 3 * DMODEL, 1.0f, 1);

        // V^T per (b,h)
        vt_kernel<<<(BB * NH * 64 * TT) / 256, 256, 0, stream>>>(qkv_hi, Vt);

        // S = Q K^T * scale  (causal tile skip)
        gemm_bt<128, true, 0, 1><<<dim3(8, 8, BB * NH), 256, 0, stream>>>(
            qkv_hi, qkv_lo, 3 * DMODEL, ZA, 64,
            qkv_hi + DMODEL, qkv_lo + DMODEL, 3 * DMODEL, ZA, 64,
            S, nullptr, nullptr, TT, ZS, (long long)TT * TT,
            nullptr, nullptr, 64, TT, 0.125f, NH);

        // causal softmax rows
        softmax_kernel<<<dim3(TT, BB * NH), 256, 0, stream>>>(S, P);

        // O = P V   (causal K limit), write bf16 hi/lo into [2048,768] at head offset
        gemm_bt<64, false, 3, 2><<<dim3(8, 1, BB * NH), 256, 0, stream>>>(
            P, nullptr, TT, ZS, (long long)TT * TT,
            Vt, nullptr, TT, ZV, (long long)64 * TT,
            nullptr, O_hi, O_lo, DMODEL, (long long)TT * DMODEL, 64,
            nullptr, nullptr, TT, 64, 1.0f, NH);

        // x = x + O @ out_w
        gemm_bt<128, true, 1, 0><<<dim3(16, 6, 1), 256, 0, stream>>>(
            O_hi, O_lo, DMODEL, 0, 0,
            wOhi, wOlo, DMODEL, 0, 0,
            xf, nullptr, nullptr, DMODEL, 0, 0,
            nullptr, xf, DMODEL, DMODEL, 1.0f, 1);

        // LN2
        ln_kernel<<<MROWS, 256, 0, stream>>>(xf, ln2_w + l2 * DMODEL, ln2_b + l2 * DMODEL, h_hi, h_lo);

        // g = gelu(h @ w1 + b1)  -> bf16 hi/lo
        gemm_bt<128, true, 4, 0><<<dim3(16, 24, 1), 256, 0, stream>>>(
            h_hi, h_lo, DMODEL, 0, 0,
            wF1hi, wF1lo, DMODEL, 0, 0,
            nullptr, g_hi, g_lo, FF, 0, 0,
            ff_b1 + l2 * FF, nullptr, DMODEL, FF, 1.0f, 1);

        // x = x + g @ w2 + b2
        gemm_bt<128, true, 2, 0><<<dim3(16, 6, 1), 256, 0, stream>>>(
            g_hi, g_lo, FF, 0, 0,
            wF2hi, wF2lo, FF, 0, 0,
            xf, nullptr, nullptr, DMODEL, 0, 0,
            ff_b2 + l2 * DMODEL, xf, FF, DMODEL, 1.0f, 1);
    }

    // final LN
    ln_kernel<<<MROWS, 256, 0, stream>>>(xf, lnf_w, lnf_b, h_hi, h_lo);

    // logits = h @ tok_emb^T  (plain bf16, fp32 out, N bounded to 50257)
    gemm_bt<128, false, 0, 0><<<dim3(16, VPAD / 128, 1), 256, 0, stream>>>(
        h_hi, nullptr, DMODEL, 0, 0,
        temb, nullptr, DMODEL, 0, 0,
        logits, nullptr, nullptr, VOCAB, 0, 0,
        nullptr, nullptr, DMODEL, VOCAB, 1.0f, 1);
}